// Round 1
// baseline (10454.803 us; speedup 1.0000x reference)
//
#include <hip/hip_runtime.h>
#include <math.h>

#define NEGB (-1e9f)

typedef float4 f4;

__device__ __forceinline__ float wsum(float v){
#pragma unroll
  for (int m = 32; m; m >>= 1) v += __shfl_xor(v, m, 64);
  return v;
}
__device__ __forceinline__ float wmaxr(float v){
#pragma unroll
  for (int m = 32; m; m >>= 1) v = fmaxf(v, __shfl_xor(v, m, 64));
  return v;
}
__device__ __forceinline__ f4 ld4(const float* p){ return *reinterpret_cast<const f4*>(p); }
__device__ __forceinline__ void st4(float* p, f4 v){ *reinterpret_cast<f4*>(p) = v; }
__device__ __forceinline__ float dot4(f4 a, f4 b){
  return a.x*b.x + a.y*b.y + a.z*b.z + a.w*b.w;
}
__device__ __forceinline__ float sigm(float x){ return 1.0f/(1.0f + expf(-x)); }

// ---------------- prologue kernels ----------------

// copy init_h -> h0, init_c -> c, zero loss. grid 256 x 256 threads (65536 elems)
__global__ __launch_bounds__(256) void k_init(const float* __restrict__ ih,
    const float* __restrict__ ic, float* __restrict__ h0, float* __restrict__ c,
    float* __restrict__ loss){
  int i = blockIdx.x*256 + threadIdx.x;
  h0[i] = ih[i];
  c[i]  = ic[i];
  if (blockIdx.x == 0 && threadIdx.x == 0) *loss = 0.f;
}

// WtgtT[e][d] = W_tgt[d][e]   (1024x1024), grid 1024 x 256
__global__ __launch_bounds__(256) void k_transpose(const float* __restrict__ in,
    float* __restrict__ out){
  __shared__ float tile[32][33];
  int bx = (blockIdx.x & 31) * 32, by = (blockIdx.x >> 5) * 32;
  int tx = threadIdx.x & 31, ty = threadIdx.x >> 5;   // ty in [0,8)
#pragma unroll
  for (int r = 0; r < 4; ++r){
    int row = ty*4 + r;
    tile[row][tx] = in[(size_t)(by + row)*1024 + bx + tx];
  }
  __syncthreads();
#pragma unroll
  for (int r = 0; r < 4; ++r){
    int row = ty*4 + r;
    out[(size_t)(bx + row)*1024 + by + tx] = tile[tx][row];
  }
}

// WcT[ep][d] = sum_e W_att[ep][e] * W_out[d][e]    grid 4096 x 256
__global__ __launch_bounds__(256) void k_wct(const float* __restrict__ W_att,
    const float* __restrict__ W_out, float* __restrict__ WcT){
  int ep = blockIdx.x >> 2;
  int dblk = blockIdx.x & 3;
  int w = threadIdx.x >> 6, lane = threadIdx.x & 63;
  int d0 = dblk*256 + w*64;
  const float* arow = W_att + (size_t)ep*1024;
  f4 af[4];
#pragma unroll
  for (int i=0;i<4;++i) af[i] = ld4(arow + i*256 + lane*4);
  float outv = 0.f;
  for (int rr=0; rr<64; ++rr){
    const float* brow = W_out + (size_t)(d0+rr)*1024;
    float acc = 0.f;
#pragma unroll
    for (int i=0;i<4;++i) acc += dot4(ld4(brow + i*256 + lane*4), af[i]);
    float s = wsum(acc);
    if (lane == rr) outv = s;
  }
  WcT[(size_t)ep*1024 + d0 + lane] = outv;
}

// ubias[ep] = sum_e W_att[ep][e]*b_out[e]   grid 4 x 256
__global__ __launch_bounds__(256) void k_ubias(const float* __restrict__ W_att,
    const float* __restrict__ b_out, float* __restrict__ ub){
  int w = threadIdx.x >> 6, lane = threadIdx.x & 63;
  int e0 = blockIdx.x*256 + w*64;
  f4 bf[4];
#pragma unroll
  for (int i=0;i<4;++i) bf[i] = ld4(b_out + i*256 + lane*4);
  float outv = 0.f;
  for (int rr=0; rr<64; ++rr){
    const float* arow = W_att + (size_t)(e0+rr)*1024;
    float acc = 0.f;
#pragma unroll
    for (int i=0;i<4;++i) acc += dot4(ld4(arow + i*256 + lane*4), bf[i]);
    float s = wsum(acc);
    if (lane == rr) outv = s;
  }
  ub[e0 + lane] = outv;
}

// ---------------- per-step kernels ----------------

// q[b][n] = h[b] . WtgtT[n] + b_tgt[n]   (n<1024)
// u[b][n-1024] = h[b] . WcT[n-1024] + ubias[n-1024]
// grid 512 (b x 8 n-blocks) x 256
__global__ __launch_bounds__(256) void k_qu(const float* __restrict__ h,
    const float* __restrict__ WtgtT, const float* __restrict__ WcT,
    const float* __restrict__ b_tgt, const float* __restrict__ ub,
    float* __restrict__ q, float* __restrict__ u){
  int b = blockIdx.x >> 3, nblk = blockIdx.x & 7;
  int w = threadIdx.x >> 6, lane = threadIdx.x & 63;
  int n0 = nblk*256 + w*64;
  const float* hb = h + (size_t)b*1024;
  f4 hf[4];
#pragma unroll
  for (int i=0;i<4;++i) hf[i] = ld4(hb + i*256 + lane*4);
  bool isq = (n0 < 1024);
  const float* W    = isq ? WtgtT : WcT;
  const float* bias = isq ? b_tgt : ub;
  int nb = isq ? n0 : (n0 - 1024);
  float outv = 0.f;
  for (int rr=0; rr<64; ++rr){
    const float* wrow = W + (size_t)(nb+rr)*1024;
    float acc = 0.f;
#pragma unroll
    for (int i=0;i<4;++i) acc += dot4(ld4(wrow + i*256 + lane*4), hf[i]);
    float s = wsum(acc) + bias[nb+rr];
    if (lane == rr) outv = s;
  }
  float* dst = (isq ? q : u) + (size_t)b*1024 + nb;
  dst[lane] = outv;
}

// masked attention over memory, online softmax, ctx out. grid 64 x 256
__global__ __launch_bounds__(256) void k_attn(const float* __restrict__ memory,
    const float* __restrict__ qbuf, const int* __restrict__ mmask,
    float* __restrict__ ctx){
  __shared__ float ctx_s[4][1024];
  __shared__ float mw[4], lw[4];
  int b = blockIdx.x;
  int w = threadIdx.x >> 6, lane = threadIdx.x & 63;
  const float* qb = qbuf + (size_t)b*1024;
  f4 qf[4];
#pragma unroll
  for (int i=0;i<4;++i) qf[i] = ld4(qb + i*256 + lane*4);
  float m = -INFINITY, l = 0.f;
  f4 ca[4];
#pragma unroll
  for (int i=0;i<4;++i){ ca[i].x=0;ca[i].y=0;ca[i].z=0;ca[i].w=0; }
  for (int rr=0; rr<64; ++rr){
    int s = w*64 + rr;
    const float* mr = memory + ((size_t)b*256 + s)*1024;
    f4 a[4];
#pragma unroll
    for (int i=0;i<4;++i) a[i] = ld4(mr + i*256 + lane*4);
    float acc = 0.f;
#pragma unroll
    for (int i=0;i<4;++i) acc += dot4(a[i], qf[i]);
    float sc = wsum(acc) + (mmask[b*256+s]==1 ? NEGB : 0.f);
    float mn = fmaxf(m, sc);
    float al = expf(m - mn);     // m=-inf first iter -> 0
    float p  = expf(sc - mn);
    l = l*al + p;
#pragma unroll
    for (int i=0;i<4;++i){
      ca[i].x = ca[i].x*al + a[i].x*p;
      ca[i].y = ca[i].y*al + a[i].y*p;
      ca[i].z = ca[i].z*al + a[i].z*p;
      ca[i].w = ca[i].w*al + a[i].w*p;
    }
    m = mn;
  }
#pragma unroll
  for (int i=0;i<4;++i) st4(&ctx_s[w][i*256 + lane*4], ca[i]);
  if (lane == 0){ mw[w] = m; lw[w] = l; }
  __syncthreads();
  int k4 = threadIdx.x*4;
  float M = fmaxf(fmaxf(mw[0],mw[1]), fmaxf(mw[2],mw[3]));
  float co0 = expf(mw[0]-M), co1 = expf(mw[1]-M), co2 = expf(mw[2]-M), co3 = expf(mw[3]-M);
  float L = co0*lw[0] + co1*lw[1] + co2*lw[2] + co3*lw[3];
  f4 t0 = ld4(&ctx_s[0][k4]), t1 = ld4(&ctx_s[1][k4]);
  f4 t2 = ld4(&ctx_s[2][k4]), t3 = ld4(&ctx_s[3][k4]);
  float inv = 1.f / L;
  f4 o;
  o.x = (co0*t0.x + co1*t1.x + co2*t2.x + co3*t3.x) * inv;
  o.y = (co0*t0.y + co1*t1.y + co2*t2.y + co3*t3.y) * inv;
  o.z = (co0*t0.z + co1*t1.z + co2*t2.z + co3*t3.z) * inv;
  o.w = (co0*t0.w + co1*t1.w + co2*t2.w + co3*t3.w) * inv;
  st4(ctx + (size_t)b*1024 + k4, o);
}

// fused gate GEMM + LSTM cell. grid 1024 (b x 16 jblk) x 256
__global__ __launch_bounds__(256) void k_gates(
    const float* __restrict__ prev_e, const float* __restrict__ node_e,
    const float* __restrict__ ctx, const float* __restrict__ h_old,
    const float* __restrict__ W_ih, const float* __restrict__ W_hh,
    const float* __restrict__ b_ih, const float* __restrict__ b_hh,
    float* __restrict__ h_new, float* __restrict__ c_io){
  int b = blockIdx.x >> 4, jblk = blockIdx.x & 15;
  int w = threadIdx.x >> 6, lane = threadIdx.x & 63;
  int j0 = jblk*64 + w*16;
  const float* pe = prev_e + (size_t)b*1024;
  const float* ne = node_e + (size_t)b*1024;
  const float* cx = ctx    + (size_t)b*1024;
  const float* hb = h_old  + (size_t)b*1024;
  f4 xf[16];
#pragma unroll
  for (int i=0;i<4;++i){
    xf[i]    = ld4(pe + i*256 + lane*4);
    xf[4+i]  = ld4(ne + i*256 + lane*4);
    xf[8+i]  = ld4(cx + i*256 + lane*4);
    xf[12+i] = ld4(hb + i*256 + lane*4);
  }
  float c_old = (lane < 16) ? c_io[(size_t)b*1024 + j0 + lane] : 0.f;
  float hn = 0.f, cn = 0.f;
  for (int jj=0; jj<16; ++jj){
    int j = j0 + jj;
    float g[4];
#pragma unroll
    for (int gg=0; gg<4; ++gg){
      int r = gg*1024 + j;
      const float* wi = W_ih + (size_t)r*3072;
      const float* wh = W_hh + (size_t)r*1024;
      f4 acc4; acc4.x=0;acc4.y=0;acc4.z=0;acc4.w=0;
#pragma unroll
      for (int i=0;i<12;++i){
        f4 wv = ld4(wi + i*256 + lane*4);
        acc4.x += wv.x*xf[i].x; acc4.y += wv.y*xf[i].y;
        acc4.z += wv.z*xf[i].z; acc4.w += wv.w*xf[i].w;
      }
#pragma unroll
      for (int i=0;i<4;++i){
        f4 wv = ld4(wh + i*256 + lane*4);
        acc4.x += wv.x*xf[12+i].x; acc4.y += wv.y*xf[12+i].y;
        acc4.z += wv.z*xf[12+i].z; acc4.w += wv.w*xf[12+i].w;
      }
      g[gg] = wsum(acc4.x+acc4.y+acc4.z+acc4.w) + b_ih[r] + b_hh[r];
    }
    if (lane == jj){
      float gi = sigm(g[0]), gf = sigm(g[1]);
      float gg2 = tanhf(g[2]), go = sigm(g[3]);
      cn = gf*c_old + gi*gg2;
      hn = go*tanhf(cn);
    }
  }
  if (lane < 16){
    h_new[(size_t)b*1024 + j0 + lane] = hn;
    c_io [(size_t)b*1024 + j0 + lane] = cn;
  }
}

// scoring heads + log-softmax + gold gather + loss accumulation. grid 64 x 256
__global__ __launch_bounds__(256) void k_scores(
    const float* __restrict__ u, const float* __restrict__ action_emb,
    const float* __restrict__ enc_col, const float* __restrict__ enc_tab,
    const int* __restrict__ col_mask, const int* __restrict__ tab_mask,
    const int* __restrict__ gold_a, const int* __restrict__ gold_c,
    const int* __restrict__ gold_t, int t, float* __restrict__ loss){
  __shared__ float s_all[208];
  __shared__ float hll[3];
  int b = blockIdx.x;
  int w = threadIdx.x >> 6, lane = threadIdx.x & 63;
  const float* ubp = u + (size_t)b*1024;
  f4 uf[4];
#pragma unroll
  for (int i=0;i<4;++i) uf[i] = ld4(ubp + i*256 + lane*4);
  for (int rr=0; rr<52; ++rr){
    int r = w*52 + rr;
    const float* src; float bias = 0.f;
    if (r < 128){
      src = action_emb + (size_t)r*1024;
    } else if (r < 192){
      int cc = r - 128;
      src = enc_col + ((size_t)b*64 + cc)*1024;
      bias = (col_mask[b*64+cc]==1) ? NEGB : 0.f;
    } else {
      int tt = r - 192;
      src = enc_tab + ((size_t)b*16 + tt)*1024;
      bias = (tab_mask[b*16+tt]==1) ? NEGB : 0.f;
    }
    float acc = 0.f;
#pragma unroll
    for (int i=0;i<4;++i) acc += dot4(ld4(src + i*256 + lane*4), uf[i]);
    float s = wsum(acc) + bias;
    if (lane == 0) s_all[r] = s;
  }
  __syncthreads();
  if (w == 0){
    float v0 = s_all[lane], v1 = s_all[64+lane];
    float M = wmaxr(fmaxf(v0, v1));
    float L = wsum(expf(v0-M) + expf(v1-M));
    if (lane == 0){ int g = gold_a[t*64+b]; hll[0] = s_all[g] - M - logf(L); }
  } else if (w == 1){
    float v = s_all[128+lane];
    float M = wmaxr(v);
    float L = wsum(expf(v-M));
    if (lane == 0){ int g = gold_c[t*64+b]; hll[1] = s_all[128+g] - M - logf(L); }
  } else if (w == 2){
    float v = (lane < 16) ? s_all[192+lane] : -INFINITY;
    float M = wmaxr(v);
    float L = wsum((lane < 16) ? expf(v-M) : 0.f);
    if (lane == 0){ int g = gold_t[t*64+b]; hll[2] = s_all[192+g] - M - logf(L); }
  }
  __syncthreads();
  if (threadIdx.x == 0) atomicAdd(loss, -(hll[0]+hll[1]+hll[2]));
}

// ---------------- launcher ----------------

extern "C" void kernel_launch(void* const* d_in, const int* in_sizes, int n_in,
                              void* d_out, int out_size, void* d_ws, size_t ws_size,
                              hipStream_t stream){
  const float* memory    = (const float*)d_in[0];
  const float* enc_col   = (const float*)d_in[1];
  const float* enc_tab   = (const float*)d_in[2];
  const float* init_h    = (const float*)d_in[3];
  const float* init_c    = (const float*)d_in[4];
  const float* prev_emb  = (const float*)d_in[5];
  const float* node_emb  = (const float*)d_in[6];
  const float* W_att     = (const float*)d_in[7];
  // d_in[8] = b_att: cancels exactly in every log-softmax head (constant shift) — unused.
  const float* W_tgt     = (const float*)d_in[9];
  const float* b_tgt     = (const float*)d_in[10];
  const float* W_out     = (const float*)d_in[11];
  const float* b_out     = (const float*)d_in[12];
  const float* W_ih      = (const float*)d_in[13];
  const float* W_hh      = (const float*)d_in[14];
  const float* b_ih      = (const float*)d_in[15];
  const float* b_hh      = (const float*)d_in[16];
  const float* action_emb= (const float*)d_in[17];
  const int*   mem_mask  = (const int*)d_in[18];
  const int*   col_mask  = (const int*)d_in[19];
  const int*   tab_mask  = (const int*)d_in[20];
  const int*   gold_a    = (const int*)d_in[21];
  const int*   gold_c    = (const int*)d_in[22];
  const int*   gold_t    = (const int*)d_in[23];

  float* ws   = (float*)d_ws;
  float* h0   = ws;                 // 65536
  float* h1   = h0 + 65536;         // 65536
  float* c    = h1 + 65536;         // 65536
  float* ctx  = c  + 65536;         // 65536
  float* q    = ctx + 65536;        // 65536
  float* u    = q  + 65536;         // 65536
  float* WtgtT= u  + 65536;         // 1048576
  float* WcT  = WtgtT + 1048576;    // 1048576
  float* ub   = WcT  + 1048576;     // 1024
  float* loss = (float*)d_out;

  k_init     <<<256, 256, 0, stream>>>(init_h, init_c, h0, c, loss);
  k_transpose<<<1024,256, 0, stream>>>(W_tgt, WtgtT);
  k_wct      <<<4096,256, 0, stream>>>(W_att, W_out, WcT);
  k_ubias    <<<4,   256, 0, stream>>>(W_att, b_out, ub);
  k_qu       <<<512, 256, 0, stream>>>(h0, WtgtT, WcT, b_tgt, ub, q, u);

  for (int t = 0; t < 24; ++t){
    float* hold = (t & 1) ? h1 : h0;
    float* hnew = (t & 1) ? h0 : h1;
    k_attn  <<<64,  256, 0, stream>>>(memory, q, mem_mask, ctx);
    k_gates <<<1024,256, 0, stream>>>(prev_emb + (size_t)t*65536,
                                      node_emb + (size_t)t*65536,
                                      ctx, hold, W_ih, W_hh, b_ih, b_hh, hnew, c);
    k_qu    <<<512, 256, 0, stream>>>(hnew, WtgtT, WcT, b_tgt, ub, q, u);
    k_scores<<<64,  256, 0, stream>>>(u, action_emb, enc_col, enc_tab,
                                      col_mask, tab_mask, gold_a, gold_c, gold_t,
                                      t, loss);
  }
}

// Round 3
// 3941.422 us; speedup vs baseline: 2.6525x; 2.6525x over previous
//
#include <hip/hip_runtime.h>
#include <math.h>

#define NEGB (-1e9f)
typedef float4 f4;

__device__ __forceinline__ float wsum(float v){
#pragma unroll
  for (int m = 32; m; m >>= 1) v += __shfl_xor(v, m, 64);
  return v;
}
__device__ __forceinline__ float wmaxr(float v){
#pragma unroll
  for (int m = 32; m; m >>= 1) v = fmaxf(v, __shfl_xor(v, m, 64));
  return v;
}
__device__ __forceinline__ f4 ld4(const float* p){ return *reinterpret_cast<const f4*>(p); }
__device__ __forceinline__ void st4(float* p, f4 v){ *reinterpret_cast<f4*>(p) = v; }
__device__ __forceinline__ float dot4(f4 a, f4 b){
  return a.x*b.x + a.y*b.y + a.z*b.z + a.w*b.w;
}
__device__ __forceinline__ float sigm(float x){ return 1.0f/(1.0f + expf(-x)); }

// ---------------- prologue kernels ----------------

__global__ __launch_bounds__(64) void k_init(float* __restrict__ loss){
  if (threadIdx.x == 0) *loss = 0.f;
}

// in [64][1024] -> out [1024][64]; grid 32
__global__ __launch_bounds__(256) void k_transpose64(const float* __restrict__ in,
    float* __restrict__ out){
  __shared__ float t64[64][33];
  int tid = threadIdx.x;
  int k0 = blockIdx.x * 32;
  int b = tid >> 2, kk = (tid & 3) * 8;
  f4 v0 = ld4(in + (size_t)b*1024 + k0 + kk);
  f4 v1 = ld4(in + (size_t)b*1024 + k0 + kk + 4);
  t64[b][kk+0]=v0.x; t64[b][kk+1]=v0.y; t64[b][kk+2]=v0.z; t64[b][kk+3]=v0.w;
  t64[b][kk+4]=v1.x; t64[b][kk+5]=v1.y; t64[b][kk+6]=v1.z; t64[b][kk+7]=v1.w;
  __syncthreads();
  int b2 = tid & 63, kg = tid >> 6;
#pragma unroll
  for (int i=0;i<8;++i){
    int kk2 = kg*8 + i;
    out[(size_t)(k0+kk2)*64 + b2] = t64[b2][kk2];
  }
}

// WcTk[d][ep] = sum_e W_att[ep][e] * W_out[d][e]    grid 4096 x 256
__global__ __launch_bounds__(256) void k_wctk(const float* __restrict__ W_att,
    const float* __restrict__ W_out, float* __restrict__ WcTk){
  int ep = blockIdx.x >> 2;
  int dblk = blockIdx.x & 3;
  int w = threadIdx.x >> 6, lane = threadIdx.x & 63;
  int d0 = dblk*256 + w*64;
  const float* arow = W_att + (size_t)ep*1024;
  f4 af[4];
#pragma unroll
  for (int i=0;i<4;++i) af[i] = ld4(arow + i*256 + lane*4);
  float outv = 0.f;
  for (int rr=0; rr<64; ++rr){
    const float* brow = W_out + (size_t)(d0+rr)*1024;
    float acc = 0.f;
#pragma unroll
    for (int i=0;i<4;++i) acc += dot4(ld4(brow + i*256 + lane*4), af[i]);
    float s = wsum(acc);
    if (lane == rr) outv = s;
  }
  WcTk[(size_t)(d0 + lane)*1024 + ep] = outv;   // k-major store
}

// ub[ep] = sum_e W_att[ep][e]*b_out[e]   grid 4 x 256
__global__ __launch_bounds__(256) void k_ubias(const float* __restrict__ W_att,
    const float* __restrict__ b_out, float* __restrict__ ub){
  int w = threadIdx.x >> 6, lane = threadIdx.x & 63;
  int e0 = blockIdx.x*256 + w*64;
  f4 bf[4];
#pragma unroll
  for (int i=0;i<4;++i) bf[i] = ld4(b_out + i*256 + lane*4);
  float outv = 0.f;
  for (int rr=0; rr<64; ++rr){
    const float* arow = W_att + (size_t)(e0+rr)*1024;
    float acc = 0.f;
#pragma unroll
    for (int i=0;i<4;++i) acc += dot4(ld4(arow + i*256 + lane*4), bf[i]);
    float s = wsum(acc);
    if (lane == rr) outv = s;
  }
  ub[e0 + lane] = outv;
}

// ---------------- per-step kernels ----------------

#define FMA4(a, s, v) { (a).x += (s)*(v).x; (a).y += (s)*(v).y; (a).z += (s)*(v).z; (a).w += (s)*(v).w; }

// Gate GEMM: part[ks][r][b] partial sums. grid 16*sk x 256.
__global__ __launch_bounds__(256) void k_gates_gemm(
    const float* __restrict__ prev_e, const float* __restrict__ node_e,
    const float* __restrict__ ctxT, const float* __restrict__ hT,
    const float* __restrict__ W_ih, const float* __restrict__ W_hh,
    float* __restrict__ part, int sk){
  __shared__ float Wl[16][260];
  __shared__ float Xl[16][68];
  int tid = threadIdx.x;
  int rt = blockIdx.x / sk, ks = blockIdx.x - rt*sk;
  int r0 = rt*256;
  int kper = 4096/sk;
  int kbeg = ks*kper, kend = kbeg + kper;
  int tx = tid & 7, ty = tid >> 3;
  int m0 = ty*8, n0 = tx*8;
  f4 acc[8][2];
#pragma unroll
  for (int i=0;i<8;++i){
    acc[i][0].x=0;acc[i][0].y=0;acc[i][0].z=0;acc[i][0].w=0;
    acc[i][1].x=0;acc[i][1].y=0;acc[i][1].z=0;acc[i][1].w=0;
  }
  for (int kc = kbeg; kc < kend; kc += 16){
    {
      const float* src = (kc < 3072) ? (W_ih + (size_t)(r0+tid)*3072 + kc)
                                     : (W_hh + (size_t)(r0+tid)*1024 + (kc-3072));
#pragma unroll
      for (int i=0;i<4;++i){
        f4 v = ld4(src + i*4);
        Wl[i*4+0][tid]=v.x; Wl[i*4+1][tid]=v.y; Wl[i*4+2][tid]=v.z; Wl[i*4+3][tid]=v.w;
      }
    }
    int sel = kc >> 10;
    if (sel <= 1){
      const float* src = (sel==0) ? prev_e : node_e;   // row-major [64][1024]
      int b = tid >> 2, kk = (tid & 3)*4;
      f4 v = ld4(src + (size_t)b*1024 + (kc & 1023) + kk);
      Xl[kk+0][b]=v.x; Xl[kk+1][b]=v.y; Xl[kk+2][b]=v.z; Xl[kk+3][b]=v.w;
    } else {
      const float* src = (sel==2) ? (ctxT + (size_t)(kc-2048)*64)
                                  : (hT  + (size_t)(kc-3072)*64);  // k-major [1024][64]
      int b = tid & 63, kg = tid >> 6;
#pragma unroll
      for (int i=0;i<4;++i){
        int kk = kg*4 + i;
        Xl[kk][b] = src[(size_t)kk*64 + b];
      }
    }
    __syncthreads();
#pragma unroll
    for (int k=0;k<16;++k){
      f4 w0 = ld4(&Wl[k][m0]);
      f4 w1 = ld4(&Wl[k][m0+4]);
      f4 x0 = ld4(&Xl[k][n0]);
      f4 x1 = ld4(&Xl[k][n0+4]);
      float wv[8] = {w0.x,w0.y,w0.z,w0.w,w1.x,w1.y,w1.z,w1.w};
#pragma unroll
      for (int i=0;i<8;++i){
        FMA4(acc[i][0], wv[i], x0);
        FMA4(acc[i][1], wv[i], x1);
      }
    }
    __syncthreads();
  }
#pragma unroll
  for (int i=0;i<8;++i){
    float* dst = part + ((size_t)ks*4096 + r0 + m0 + i)*64 + n0;
    st4(dst, acc[i][0]); st4(dst+4, acc[i][1]);
  }
}

// q/u GEMM. grid 8*sk x 256. Rows n<1024: W_tgt (k-major), else WcTk.
__global__ __launch_bounds__(256) void k_qu_gemm(
    const float* __restrict__ hT, const float* __restrict__ W_tgt,
    const float* __restrict__ WcTk, float* __restrict__ part, int sk){
  __shared__ float Wl[16][260];
  __shared__ float Xl[16][68];
  int tid = threadIdx.x;
  int rt = blockIdx.x / sk, ks = blockIdx.x - rt*sk;
  int n0g = rt*256;
  int kper = 1024/sk;
  int kbeg = ks*kper, kend = kbeg + kper;
  int tx = tid & 7, ty = tid >> 3;
  int m0 = ty*8, n0 = tx*8;
  f4 acc[8][2];
#pragma unroll
  for (int i=0;i<8;++i){
    acc[i][0].x=0;acc[i][0].y=0;acc[i][0].z=0;acc[i][0].w=0;
    acc[i][1].x=0;acc[i][1].y=0;acc[i][1].z=0;acc[i][1].w=0;
  }
  const float* Wsrc = (rt < 4) ? (W_tgt + n0g) : (WcTk + (n0g - 1024));
  for (int kc = kbeg; kc < kend; kc += 16){
    {
      int kk = tid >> 4, mb = (tid & 15)*4;
#pragma unroll
      for (int i=0;i<4;++i){
        f4 v = ld4(Wsrc + (size_t)(kc+kk)*1024 + mb + i*64);
        *reinterpret_cast<f4*>(&Wl[kk][mb + i*64]) = v;
      }
    }
    {
      int b = tid & 63, kg = tid >> 6;
#pragma unroll
      for (int i=0;i<4;++i){
        int kk = kg*4 + i;
        Xl[kk][b] = hT[(size_t)(kc+kk)*64 + b];
      }
    }
    __syncthreads();
#pragma unroll
    for (int k=0;k<16;++k){
      f4 w0 = ld4(&Wl[k][m0]);
      f4 w1 = ld4(&Wl[k][m0+4]);
      f4 x0 = ld4(&Xl[k][n0]);
      f4 x1 = ld4(&Xl[k][n0+4]);
      float wv[8] = {w0.x,w0.y,w0.z,w0.w,w1.x,w1.y,w1.z,w1.w};
#pragma unroll
      for (int i=0;i<8;++i){
        FMA4(acc[i][0], wv[i], x0);
        FMA4(acc[i][1], wv[i], x1);
      }
    }
    __syncthreads();
  }
#pragma unroll
  for (int i=0;i<8;++i){
    float* dst = part + ((size_t)ks*2048 + n0g + m0 + i)*64 + n0;
    st4(dst, acc[i][0]); st4(dst+4, acc[i][1]);
  }
}

// reduce + bias for q/u. grid 512 x 256
__global__ __launch_bounds__(256) void k_qu_reduce(const float* __restrict__ part,
    const float* __restrict__ b_tgt, const float* __restrict__ ub,
    float* __restrict__ q, float* __restrict__ u, int sk){
  int idx = blockIdx.x*256 + threadIdx.x;
  int b = idx & 63, n = idx >> 6;
  float s = 0.f;
  for (int ks=0; ks<sk; ++ks) s += part[((size_t)ks*2048 + n)*64 + b];
  if (n < 1024) q[(size_t)b*1024 + n] = s + b_tgt[n];
  else          u[(size_t)b*1024 + n - 1024] = s + ub[n - 1024];
}

// reduce + LSTM pointwise. grid 256 x 256
__global__ __launch_bounds__(256) void k_lstm(const float* __restrict__ part,
    const float* __restrict__ b_ih, const float* __restrict__ b_hh,
    float* __restrict__ hT, float* __restrict__ cT, int sk){
  int idx = blockIdx.x*256 + threadIdx.x;   // b fastest
  int b = idx & 63, j = idx >> 6;
  float g[4];
#pragma unroll
  for (int gg=0; gg<4; ++gg){
    int r = gg*1024 + j;
    float s = b_ih[r] + b_hh[r];
    for (int ks=0; ks<sk; ++ks) s += part[((size_t)ks*4096 + r)*64 + b];
    g[gg] = s;
  }
  float c_old = cT[idx];
  float cn = sigm(g[1])*c_old + sigm(g[0])*tanhf(g[2]);
  float hn = sigm(g[3])*tanhf(cn);
  hT[idx] = hn;
  cT[idx] = cn;
}

// attention partials. grid 512 (b x 8 chunks) x 256
__global__ __launch_bounds__(256) void k_attn_part(const float* __restrict__ memory,
    const float* __restrict__ q, const int* __restrict__ mmask,
    float* __restrict__ pa){
  __shared__ float cs[4][1024];
  __shared__ float mw[4], lw[4];
  int b = blockIdx.x >> 3, sc = blockIdx.x & 7;
  int w = threadIdx.x >> 6, lane = threadIdx.x & 63;
  const float* qb = q + (size_t)b*1024;
  f4 qf[4];
#pragma unroll
  for (int i=0;i<4;++i) qf[i] = ld4(qb + i*256 + lane*4);
  float m = -INFINITY, l = 0.f;
  f4 ca[4];
#pragma unroll
  for (int i=0;i<4;++i){ ca[i].x=0;ca[i].y=0;ca[i].z=0;ca[i].w=0; }
  for (int rr=0; rr<8; ++rr){
    int s = sc*32 + w*8 + rr;
    const float* mr = memory + ((size_t)b*256 + s)*1024;
    f4 a[4];
#pragma unroll
    for (int i=0;i<4;++i) a[i] = ld4(mr + i*256 + lane*4);
    float acc = 0.f;
#pragma unroll
    for (int i=0;i<4;++i) acc += dot4(a[i], qf[i]);
    float sv = wsum(acc) + (mmask[b*256+s]==1 ? NEGB : 0.f);
    float mn = fmaxf(m, sv);
    float al = expf(m - mn);
    float p  = expf(sv - mn);
    l = l*al + p;
#pragma unroll
    for (int i=0;i<4;++i){
      ca[i].x = ca[i].x*al + a[i].x*p;
      ca[i].y = ca[i].y*al + a[i].y*p;
      ca[i].z = ca[i].z*al + a[i].z*p;
      ca[i].w = ca[i].w*al + a[i].w*p;
    }
    m = mn;
  }
#pragma unroll
  for (int i=0;i<4;++i) st4(&cs[w][i*256 + lane*4], ca[i]);
  if (lane == 0){ mw[w] = m; lw[w] = l; }
  __syncthreads();
  int k4 = threadIdx.x*4;
  float M = fmaxf(fmaxf(mw[0],mw[1]), fmaxf(mw[2],mw[3]));
  float c0 = expf(mw[0]-M), c1 = expf(mw[1]-M), c2 = expf(mw[2]-M), c3 = expf(mw[3]-M);
  float L = c0*lw[0] + c1*lw[1] + c2*lw[2] + c3*lw[3];
  f4 t0 = ld4(&cs[0][k4]), t1 = ld4(&cs[1][k4]);
  f4 t2 = ld4(&cs[2][k4]), t3 = ld4(&cs[3][k4]);
  f4 o;
  o.x = c0*t0.x + c1*t1.x + c2*t2.x + c3*t3.x;
  o.y = c0*t0.y + c1*t1.y + c2*t2.y + c3*t3.y;
  o.z = c0*t0.z + c1*t1.z + c2*t2.z + c3*t3.z;
  o.w = c0*t0.w + c1*t1.w + c2*t2.w + c3*t3.w;
  float* pb = pa + (size_t)(b*8+sc)*1040;
  st4(pb + k4, o);
  if (threadIdx.x == 0){ pb[1024] = M; pb[1025] = L; }
}

// merge 8 partials -> ctxT [1024][64]. grid 64 x 256
__global__ __launch_bounds__(256) void k_attn_merge(const float* __restrict__ pa,
    float* __restrict__ ctxT){
  int b = blockIdx.x;
  int tid = threadIdx.x;
  const float* pb = pa + (size_t)b*8*1040;
  float mm[8], ll[8];
#pragma unroll
  for (int s=0;s<8;++s){ mm[s] = pb[s*1040 + 1024]; ll[s] = pb[s*1040 + 1025]; }
  float M = mm[0];
#pragma unroll
  for (int s=1;s<8;++s) M = fmaxf(M, mm[s]);
  float co[8], L = 0.f;
#pragma unroll
  for (int s=0;s<8;++s){ co[s] = expf(mm[s]-M); L += co[s]*ll[s]; }
  float inv = 1.f / L;
  int k4 = tid*4;
#pragma unroll
  for (int i=0;i<4;++i){
    int k = k4 + i;
    float v = 0.f;
#pragma unroll
    for (int s=0;s<8;++s) v += co[s]*pb[s*1040 + k];
    ctxT[(size_t)k*64 + b] = v * inv;
  }
}

// scoring heads + log-softmax + loss. grid 64 x 256
__global__ __launch_bounds__(256) void k_scores(
    const float* __restrict__ u, const float* __restrict__ action_emb,
    const float* __restrict__ enc_col, const float* __restrict__ enc_tab,
    const int* __restrict__ col_mask, const int* __restrict__ tab_mask,
    const int* __restrict__ gold_a, const int* __restrict__ gold_c,
    const int* __restrict__ gold_t, int t, float* __restrict__ loss){
  __shared__ float s_all[208];
  __shared__ float hll[3];
  int b = blockIdx.x;
  int w = threadIdx.x >> 6, lane = threadIdx.x & 63;
  const float* ubp = u + (size_t)b*1024;
  f4 uf[4];
#pragma unroll
  for (int i=0;i<4;++i) uf[i] = ld4(ubp + i*256 + lane*4);
  for (int rr=0; rr<52; ++rr){
    int r = w*52 + rr;
    const float* src; float bias = 0.f;
    if (r < 128){
      src = action_emb + (size_t)r*1024;
    } else if (r < 192){
      int cc = r - 128;
      src = enc_col + ((size_t)b*64 + cc)*1024;
      bias = (col_mask[b*64+cc]==1) ? NEGB : 0.f;
    } else {
      int tt = r - 192;
      src = enc_tab + ((size_t)b*16 + tt)*1024;
      bias = (tab_mask[b*16+tt]==1) ? NEGB : 0.f;
    }
    float acc = 0.f;
#pragma unroll
    for (int i=0;i<4;++i) acc += dot4(ld4(src + i*256 + lane*4), uf[i]);
    float s = wsum(acc) + bias;
    if (lane == 0) s_all[r] = s;
  }
  __syncthreads();
  if (w == 0){
    float v0 = s_all[lane], v1 = s_all[64+lane];
    float M = wmaxr(fmaxf(v0, v1));
    float L = wsum(expf(v0-M) + expf(v1-M));
    if (lane == 0){ int g = gold_a[t*64+b]; hll[0] = s_all[g] - M - logf(L); }
  } else if (w == 1){
    float v = s_all[128+lane];
    float M = wmaxr(v);
    float L = wsum(expf(v-M));
    if (lane == 0){ int g = gold_c[t*64+b]; hll[1] = s_all[128+g] - M - logf(L); }
  } else if (w == 2){
    float v = (lane < 16) ? s_all[192+lane] : -INFINITY;
    float M = wmaxr(v);
    float L = wsum((lane < 16) ? expf(v-M) : 0.f);
    if (lane == 0){ int g = gold_t[t*64+b]; hll[2] = s_all[192+g] - M - logf(L); }
  }
  __syncthreads();
  if (threadIdx.x == 0) atomicAdd(loss, -(hll[0]+hll[1]+hll[2]));
}

// ---------------- launcher ----------------

extern "C" void kernel_launch(void* const* d_in, const int* in_sizes, int n_in,
                              void* d_out, int out_size, void* d_ws, size_t ws_size,
                              hipStream_t stream){
  const float* memory    = (const float*)d_in[0];
  const float* enc_col   = (const float*)d_in[1];
  const float* enc_tab   = (const float*)d_in[2];
  const float* init_h    = (const float*)d_in[3];
  const float* init_c    = (const float*)d_in[4];
  const float* prev_emb  = (const float*)d_in[5];
  const float* node_emb  = (const float*)d_in[6];
  const float* W_att     = (const float*)d_in[7];
  // d_in[8] = b_att: cancels exactly in every log-softmax head — unused.
  const float* W_tgt     = (const float*)d_in[9];
  const float* b_tgt     = (const float*)d_in[10];
  const float* W_out     = (const float*)d_in[11];
  const float* b_out     = (const float*)d_in[12];
  const float* W_ih      = (const float*)d_in[13];
  const float* W_hh      = (const float*)d_in[14];
  const float* b_ih      = (const float*)d_in[15];
  const float* b_hh      = (const float*)d_in[16];
  const float* action_emb= (const float*)d_in[17];
  const int*   mem_mask  = (const int*)d_in[18];
  const int*   col_mask  = (const int*)d_in[19];
  const int*   tab_mask  = (const int*)d_in[20];
  const int*   gold_a    = (const int*)d_in[21];
  const int*   gold_c    = (const int*)d_in[22];
  const int*   gold_t    = (const int*)d_in[23];

  float* ws   = (float*)d_ws;
  float* WcTk = ws;                      // 1048576
  float* ub   = WcTk + 1048576;          // 1024
  float* hT   = ub   + 1024;             // 65536
  float* cT   = hT   + 65536;            // 65536
  float* q    = cT   + 65536;            // 65536
  float* u    = q    + 65536;            // 65536
  float* ctxT = u    + 65536;            // 65536
  float* pa   = ctxT + 65536;            // 532480
  float* part = pa   + 532480;           // sk*4096*64
  float* loss = (float*)d_out;

  size_t fixedf = 1048576 + 1024 + (size_t)5*65536 + 532480;
  size_t availf = (ws_size/4 > fixedf) ? (ws_size/4 - fixedf) : 0;
  int sk = 16;
  if (availf < (size_t)16*4096*64) sk = 8;
  if (availf < (size_t)8*4096*64)  sk = 4;

  k_init       <<<1,   64, 0, stream>>>(loss);
  k_transpose64<<<32, 256, 0, stream>>>(init_h, hT);
  k_transpose64<<<32, 256, 0, stream>>>(init_c, cT);
  k_wctk       <<<4096,256,0, stream>>>(W_att, W_out, WcTk);
  k_ubias      <<<4,  256, 0, stream>>>(W_att, b_out, ub);
  k_qu_gemm    <<<8*sk,256,0, stream>>>(hT, W_tgt, WcTk, part, sk);
  k_qu_reduce  <<<512,256, 0, stream>>>(part, b_tgt, ub, q, u, sk);

  for (int t = 0; t < 24; ++t){
    k_attn_part <<<512, 256, 0, stream>>>(memory, q, mem_mask, pa);
    k_attn_merge<<<64,  256, 0, stream>>>(pa, ctxT);
    k_gates_gemm<<<16*sk,256,0, stream>>>(prev_emb + (size_t)t*65536,
                                          node_emb + (size_t)t*65536,
                                          ctxT, hT, W_ih, W_hh, part, sk);
    k_lstm      <<<256, 256, 0, stream>>>(part, b_ih, b_hh, hT, cT, sk);
    k_qu_gemm   <<<8*sk,256,0, stream>>>(hT, W_tgt, WcTk, part, sk);
    k_qu_reduce <<<512, 256, 0, stream>>>(part, b_tgt, ub, q, u, sk);
    k_scores    <<<64,  256, 0, stream>>>(u, action_emb, enc_col, enc_tab,
                                          col_mask, tab_mask, gold_a, gold_c, gold_t,
                                          t, loss);
  }
}

// Round 4
// 3156.118 us; speedup vs baseline: 3.3126x; 1.2488x over previous
//
#include <hip/hip_runtime.h>
#include <math.h>

#define NEGB (-1e9f)
typedef float4 f4;

__device__ __forceinline__ float wsum(float v){
#pragma unroll
  for (int m = 32; m; m >>= 1) v += __shfl_xor(v, m, 64);
  return v;
}
__device__ __forceinline__ float wmaxr(float v){
#pragma unroll
  for (int m = 32; m; m >>= 1) v = fmaxf(v, __shfl_xor(v, m, 64));
  return v;
}
__device__ __forceinline__ f4 ld4(const float* p){ return *reinterpret_cast<const f4*>(p); }
__device__ __forceinline__ void st4(float* p, f4 v){ *reinterpret_cast<f4*>(p) = v; }
__device__ __forceinline__ float dot4(f4 a, f4 b){
  return a.x*b.x + a.y*b.y + a.z*b.z + a.w*b.w;
}
__device__ __forceinline__ float sigm(float x){ return 1.0f/(1.0f + __expf(-x)); }

#define FMA4(a, s, v) { (a).x += (s)*(v).x; (a).y += (s)*(v).y; (a).z += (s)*(v).z; (a).w += (s)*(v).w; }

// ---------------- prologue kernels ----------------

__global__ __launch_bounds__(64) void k_init(float* __restrict__ loss){
  if (threadIdx.x == 0) *loss = 0.f;
}

// in [64][1024] -> out [1024][64]; grid 32
__global__ __launch_bounds__(256) void k_transpose64(const float* __restrict__ in,
    float* __restrict__ out){
  __shared__ float t64[64][33];
  int tid = threadIdx.x;
  int k0 = blockIdx.x * 32;
  int b = tid >> 2, kk = (tid & 3) * 8;
  f4 v0 = ld4(in + (size_t)b*1024 + k0 + kk);
  f4 v1 = ld4(in + (size_t)b*1024 + k0 + kk + 4);
  t64[b][kk+0]=v0.x; t64[b][kk+1]=v0.y; t64[b][kk+2]=v0.z; t64[b][kk+3]=v0.w;
  t64[b][kk+4]=v1.x; t64[b][kk+5]=v1.y; t64[b][kk+6]=v1.z; t64[b][kk+7]=v1.w;
  __syncthreads();
  int b2 = tid & 63, kg = tid >> 6;
#pragma unroll
  for (int i=0;i<8;++i){
    int kk2 = kg*8 + i;
    out[(size_t)(k0+kk2)*64 + b2] = t64[b2][kk2];
  }
}

// WcTk[d][ep] = sum_e W_out[d][e] * W_att[ep][e]. Tiled NT GEMM, 64x64 tile,
// 4x4/thread, K=1024, grid 256 (16 d-tiles x 16 ep-tiles).
__global__ __launch_bounds__(256) void k_wctk2(const float* __restrict__ W_att,
    const float* __restrict__ W_out, float* __restrict__ WcTk){
  __shared__ float Al[16][68];
  __shared__ float Bl[16][68];
  int tid = threadIdx.x;
  int d0 = (blockIdx.x >> 4) * 64, ep0 = (blockIdx.x & 15) * 64;
  int srow = tid >> 2, skk = (tid & 3) * 4;
  int m0 = (tid >> 4) * 4, n0 = (tid & 15) * 4;
  f4 acc[4];
#pragma unroll
  for (int i=0;i<4;++i){ acc[i].x=0;acc[i].y=0;acc[i].z=0;acc[i].w=0; }
  f4 pa = ld4(W_out + (size_t)(d0+srow)*1024 + skk);
  f4 pb = ld4(W_att + (size_t)(ep0+srow)*1024 + skk);
  for (int kc = 0; kc < 1024; kc += 16){
#pragma unroll
    for (int j=0;j<4;++j){
      (&Al[skk][srow])[j*68] = (&pa.x)[j];
      (&Bl[skk][srow])[j*68] = (&pb.x)[j];
    }
    __syncthreads();
    if (kc + 16 < 1024){
      pa = ld4(W_out + (size_t)(d0+srow)*1024 + kc + 16 + skk);
      pb = ld4(W_att + (size_t)(ep0+srow)*1024 + kc + 16 + skk);
    }
#pragma unroll
    for (int k=0;k<16;++k){
      f4 a4 = ld4(&Al[k][m0]);
      f4 b4 = ld4(&Bl[k][n0]);
      FMA4(acc[0], a4.x, b4);
      FMA4(acc[1], a4.y, b4);
      FMA4(acc[2], a4.z, b4);
      FMA4(acc[3], a4.w, b4);
    }
    __syncthreads();
  }
#pragma unroll
  for (int i=0;i<4;++i)
    st4(WcTk + (size_t)(d0+m0+i)*1024 + ep0 + n0, acc[i]);
}

// ub[ep] = dot(W_att[ep,:], b_out). grid 256 x 256 (one wave per ep).
__global__ __launch_bounds__(256) void k_ubias2(const float* __restrict__ W_att,
    const float* __restrict__ b_out, float* __restrict__ ub){
  int w = threadIdx.x >> 6, lane = threadIdx.x & 63;
  int ep = blockIdx.x*4 + w;
  const float* arow = W_att + (size_t)ep*1024;
  float acc = 0.f;
#pragma unroll
  for (int i=0;i<4;++i)
    acc += dot4(ld4(arow + i*256 + lane*4), ld4(b_out + i*256 + lane*4));
  float s = wsum(acc);
  if (lane == 0) ub[ep] = s;
}

// ---------------- per-step kernels ----------------

// q/u GEMM partials: rows n<1024 from W_tgt[d][n] (k-major), else WcTk[d][ep].
// X = hT [1024][64]. 64x64 tile, 4x4/thread, grid 32*SKQ. SKQ=8.
#define SKQ 8
__global__ __launch_bounds__(256) void k_qu_gemm(
    const float* __restrict__ hT, const float* __restrict__ W_tgt,
    const float* __restrict__ WcTk, float* __restrict__ part){
  __shared__ float Al[16][68];
  __shared__ float Xl[16][68];
  int tid = threadIdx.x;
  int rt = blockIdx.x >> 3, ks = blockIdx.x & 7;
  int n0g = rt*64;
  int kbeg = ks*128;
  int skk = tid >> 4, sn4 = (tid & 15) * 4;
  int m0 = (tid >> 4) * 4, n0 = (tid & 15) * 4;
  const float* Wsrc = (rt < 16) ? (W_tgt + n0g) : (WcTk + (n0g - 1024));
  f4 acc[4];
#pragma unroll
  for (int i=0;i<4;++i){ acc[i].x=0;acc[i].y=0;acc[i].z=0;acc[i].w=0; }
  f4 pa = ld4(Wsrc + (size_t)(kbeg+skk)*1024 + sn4);
  f4 px = ld4(hT + (size_t)(kbeg+skk)*64 + sn4);
  for (int kc = kbeg; kc < kbeg+128; kc += 16){
    st4(&Al[skk][sn4], pa);
    st4(&Xl[skk][sn4], px);
    __syncthreads();
    if (kc + 16 < kbeg+128){
      pa = ld4(Wsrc + (size_t)(kc+16+skk)*1024 + sn4);
      px = ld4(hT + (size_t)(kc+16+skk)*64 + sn4);
    }
#pragma unroll
    for (int k=0;k<16;++k){
      f4 a4 = ld4(&Al[k][m0]);
      f4 x4 = ld4(&Xl[k][n0]);
      FMA4(acc[0], a4.x, x4);
      FMA4(acc[1], a4.y, x4);
      FMA4(acc[2], a4.z, x4);
      FMA4(acc[3], a4.w, x4);
    }
    __syncthreads();
  }
#pragma unroll
  for (int i=0;i<4;++i)
    st4(part + ((size_t)ks*2048 + n0g + m0 + i)*64 + n0, acc[i]);
}

// reduce + bias for q/u. grid 512 x 256
__global__ __launch_bounds__(256) void k_qu_reduce(const float* __restrict__ part,
    const float* __restrict__ b_tgt, const float* __restrict__ ub,
    float* __restrict__ q, float* __restrict__ u){
  int idx = blockIdx.x*256 + threadIdx.x;
  int b = idx & 63, n = idx >> 6;
  float s = 0.f;
#pragma unroll
  for (int ks=0; ks<SKQ; ++ks) s += part[((size_t)ks*2048 + n)*64 + b];
  if (n < 1024) q[(size_t)b*1024 + n] = s + b_tgt[n];
  else          u[(size_t)b*1024 + n - 1024] = s + ub[n - 1024];
}

// Gate GEMM partials: G[4096][64] = [W_ih|W_hh] x [prev;node;ctxT;hT].
// M-tile 128, 4x8/thread, grid 32*sk x 256.
__device__ __forceinline__ f4 gx_load(const float* prev_e, const float* node_e,
    const float* ctxT, const float* hT, int kc, int tid){
  int sel = kc >> 10;
  if (sel <= 1){
    const float* src = (sel==0) ? prev_e : node_e;       // [64][1024] row-major
    int b = tid >> 2, kk = (tid & 3)*4;
    return ld4(src + (size_t)b*1024 + (kc & 1023) + kk);
  } else {
    const float* src = (sel==2) ? (ctxT + (size_t)(kc-2048)*64)
                                : (hT  + (size_t)(kc-3072)*64);  // [1024][64] k-major
    int kk = tid >> 4, b4 = (tid & 15)*4;
    return ld4(src + (size_t)kk*64 + b4);
  }
}
__device__ __forceinline__ void gx_store(float Xl[16][68], f4 v, int kc, int tid){
  if ((kc >> 10) <= 1){
    int b = tid >> 2, kk = (tid & 3)*4;
    Xl[kk+0][b]=v.x; Xl[kk+1][b]=v.y; Xl[kk+2][b]=v.z; Xl[kk+3][b]=v.w;
  } else {
    int kk = tid >> 4, b4 = (tid & 15)*4;
    st4(&Xl[kk][b4], v);
  }
}
__device__ __forceinline__ void gw_load(const float* W_ih, const float* W_hh,
    int r, int kc, int c8, f4* w){
  const float* src = (kc < 3072) ? (W_ih + (size_t)r*3072 + kc + c8)
                                 : (W_hh + (size_t)r*1024 + (kc-3072) + c8);
  w[0] = ld4(src); w[1] = ld4(src + 4);
}

__global__ __launch_bounds__(256) void k_gates_gemm(
    const float* __restrict__ prev_e, const float* __restrict__ node_e,
    const float* __restrict__ ctxT, const float* __restrict__ hT,
    const float* __restrict__ W_ih, const float* __restrict__ W_hh,
    float* __restrict__ part, int sk){
  __shared__ float Wl[16][132];
  __shared__ float Xl[16][68];
  int tid = threadIdx.x;
  int rt = blockIdx.x / sk, ks = blockIdx.x - rt*sk;
  int r0 = rt*128;
  int kper = 4096/sk;
  int kbeg = ks*kper, kend = kbeg + kper;
  int srow = tid >> 1, c8 = (tid & 1)*8;   // stage: row r0+srow, cols c8..c8+7
  int m0 = (tid >> 3)*4, n0 = (tid & 7)*8;
  f4 acc[4][2];
#pragma unroll
  for (int i=0;i<4;++i){
    acc[i][0].x=0;acc[i][0].y=0;acc[i][0].z=0;acc[i][0].w=0;
    acc[i][1].x=0;acc[i][1].y=0;acc[i][1].z=0;acc[i][1].w=0;
  }
  f4 pw[2];
  gw_load(W_ih, W_hh, r0+srow, kbeg, c8, pw);
  f4 px = gx_load(prev_e, node_e, ctxT, hT, kbeg, tid);
  for (int kc = kbeg; kc < kend; kc += 16){
#pragma unroll
    for (int j=0;j<4;++j){
      Wl[c8+j][srow]   = (&pw[0].x)[j];
      Wl[c8+4+j][srow] = (&pw[1].x)[j];
    }
    gx_store(Xl, px, kc, tid);
    __syncthreads();
    if (kc + 16 < kend){
      gw_load(W_ih, W_hh, r0+srow, kc+16, c8, pw);
      px = gx_load(prev_e, node_e, ctxT, hT, kc+16, tid);
    }
#pragma unroll
    for (int k=0;k<16;++k){
      f4 w4 = ld4(&Wl[k][m0]);
      f4 x0 = ld4(&Xl[k][n0]);
      f4 x1 = ld4(&Xl[k][n0+4]);
      FMA4(acc[0][0], w4.x, x0); FMA4(acc[0][1], w4.x, x1);
      FMA4(acc[1][0], w4.y, x0); FMA4(acc[1][1], w4.y, x1);
      FMA4(acc[2][0], w4.z, x0); FMA4(acc[2][1], w4.z, x1);
      FMA4(acc[3][0], w4.w, x0); FMA4(acc[3][1], w4.w, x1);
    }
    __syncthreads();
  }
#pragma unroll
  for (int i=0;i<4;++i){
    float* dst = part + ((size_t)ks*4096 + r0 + m0 + i)*64 + n0;
    st4(dst, acc[i][0]); st4(dst+4, acc[i][1]);
  }
}

// reduce + LSTM pointwise. grid 256 x 256
__global__ __launch_bounds__(256) void k_lstm(const float* __restrict__ part,
    const float* __restrict__ b_ih, const float* __restrict__ b_hh,
    float* __restrict__ hT, float* __restrict__ cT, int sk){
  int idx = blockIdx.x*256 + threadIdx.x;   // b fastest
  int b = idx & 63, j = idx >> 6;
  float g[4];
#pragma unroll
  for (int gg=0; gg<4; ++gg){
    int r = gg*1024 + j;
    float s = b_ih[r] + b_hh[r];
    for (int ks=0; ks<sk; ++ks) s += part[((size_t)ks*4096 + r)*64 + b];
    g[gg] = s;
  }
  float c_old = cT[idx];
  float cn = sigm(g[1])*c_old + sigm(g[0])*tanhf(g[2]);
  float hn = sigm(g[3])*tanhf(cn);
  hT[idx] = hn;
  cT[idx] = cn;
}

// attention partials. grid 512 (b x 8 chunks) x 256
__global__ __launch_bounds__(256) void k_attn_part(const float* __restrict__ memory,
    const float* __restrict__ q, const int* __restrict__ mmask,
    float* __restrict__ pa){
  __shared__ float cs[4][1024];
  __shared__ float mw[4], lw[4];
  int b = blockIdx.x >> 3, sc = blockIdx.x & 7;
  int w = threadIdx.x >> 6, lane = threadIdx.x & 63;
  const float* qb = q + (size_t)b*1024;
  f4 qf[4];
#pragma unroll
  for (int i=0;i<4;++i) qf[i] = ld4(qb + i*256 + lane*4);
  float m = -INFINITY, l = 0.f;
  f4 ca[4];
#pragma unroll
  for (int i=0;i<4;++i){ ca[i].x=0;ca[i].y=0;ca[i].z=0;ca[i].w=0; }
  for (int rr=0; rr<8; ++rr){
    int s = sc*32 + w*8 + rr;
    const float* mr = memory + ((size_t)b*256 + s)*1024;
    f4 a[4];
#pragma unroll
    for (int i=0;i<4;++i) a[i] = ld4(mr + i*256 + lane*4);
    float acc = 0.f;
#pragma unroll
    for (int i=0;i<4;++i) acc += dot4(a[i], qf[i]);
    float sv = wsum(acc) + (mmask[b*256+s]==1 ? NEGB : 0.f);
    float mn = fmaxf(m, sv);
    float al = __expf(m - mn);
    float p  = __expf(sv - mn);
    l = l*al + p;
#pragma unroll
    for (int i=0;i<4;++i){
      ca[i].x = ca[i].x*al + a[i].x*p;
      ca[i].y = ca[i].y*al + a[i].y*p;
      ca[i].z = ca[i].z*al + a[i].z*p;
      ca[i].w = ca[i].w*al + a[i].w*p;
    }
    m = mn;
  }
#pragma unroll
  for (int i=0;i<4;++i) st4(&cs[w][i*256 + lane*4], ca[i]);
  if (lane == 0){ mw[w] = m; lw[w] = l; }
  __syncthreads();
  int k4 = threadIdx.x*4;
  float M = fmaxf(fmaxf(mw[0],mw[1]), fmaxf(mw[2],mw[3]));
  float c0 = __expf(mw[0]-M), c1 = __expf(mw[1]-M);
  float c2 = __expf(mw[2]-M), c3 = __expf(mw[3]-M);
  float L = c0*lw[0] + c1*lw[1] + c2*lw[2] + c3*lw[3];
  f4 t0 = ld4(&cs[0][k4]), t1 = ld4(&cs[1][k4]);
  f4 t2 = ld4(&cs[2][k4]), t3 = ld4(&cs[3][k4]);
  f4 o;
  o.x = c0*t0.x + c1*t1.x + c2*t2.x + c3*t3.x;
  o.y = c0*t0.y + c1*t1.y + c2*t2.y + c3*t3.y;
  o.z = c0*t0.z + c1*t1.z + c2*t2.z + c3*t3.z;
  o.w = c0*t0.w + c1*t1.w + c2*t2.w + c3*t3.w;
  float* pb = pa + (size_t)(b*8+sc)*1040;
  st4(pb + k4, o);
  if (threadIdx.x == 0){ pb[1024] = M; pb[1025] = L; }
}

// merge 8 partials -> ctxT [1024][64]. grid 64 x 256
__global__ __launch_bounds__(256) void k_attn_merge(const float* __restrict__ pa,
    float* __restrict__ ctxT){
  int b = blockIdx.x;
  int tid = threadIdx.x;
  const float* pb = pa + (size_t)b*8*1040;
  float mm[8], ll[8];
#pragma unroll
  for (int s=0;s<8;++s){ mm[s] = pb[s*1040 + 1024]; ll[s] = pb[s*1040 + 1025]; }
  float M = mm[0];
#pragma unroll
  for (int s=1;s<8;++s) M = fmaxf(M, mm[s]);
  float co[8], L = 0.f;
#pragma unroll
  for (int s=0;s<8;++s){ co[s] = __expf(mm[s]-M); L += co[s]*ll[s]; }
  float inv = 1.f / L;
  int k4 = tid*4;
#pragma unroll
  for (int i=0;i<4;++i){
    int k = k4 + i;
    float v = 0.f;
#pragma unroll
    for (int s=0;s<8;++s) v += co[s]*pb[s*1040 + k];
    ctxT[(size_t)k*64 + b] = v * inv;
  }
}

// scoring heads + log-softmax + loss. grid 64 x 256
__global__ __launch_bounds__(256) void k_scores(
    const float* __restrict__ u, const float* __restrict__ action_emb,
    const float* __restrict__ enc_col, const float* __restrict__ enc_tab,
    const int* __restrict__ col_mask, const int* __restrict__ tab_mask,
    const int* __restrict__ gold_a, const int* __restrict__ gold_c,
    const int* __restrict__ gold_t, int t, float* __restrict__ loss){
  __shared__ float s_all[208];
  __shared__ float hll[3];
  int b = blockIdx.x;
  int w = threadIdx.x >> 6, lane = threadIdx.x & 63;
  const float* ubp = u + (size_t)b*1024;
  f4 uf[4];
#pragma unroll
  for (int i=0;i<4;++i) uf[i] = ld4(ubp + i*256 + lane*4);
  for (int rr=0; rr<52; ++rr){
    int r = w*52 + rr;
    const float* src; float bias = 0.f;
    if (r < 128){
      src = action_emb + (size_t)r*1024;
    } else if (r < 192){
      int cc = r - 128;
      src = enc_col + ((size_t)b*64 + cc)*1024;
      bias = (col_mask[b*64+cc]==1) ? NEGB : 0.f;
    } else {
      int tt = r - 192;
      src = enc_tab + ((size_t)b*16 + tt)*1024;
      bias = (tab_mask[b*16+tt]==1) ? NEGB : 0.f;
    }
    float acc = 0.f;
#pragma unroll
    for (int i=0;i<4;++i) acc += dot4(ld4(src + i*256 + lane*4), uf[i]);
    float s = wsum(acc) + bias;
    if (lane == 0) s_all[r] = s;
  }
  __syncthreads();
  if (w == 0){
    float v0 = s_all[lane], v1 = s_all[64+lane];
    float M = wmaxr(fmaxf(v0, v1));
    float L = wsum(__expf(v0-M) + __expf(v1-M));
    if (lane == 0){ int g = gold_a[t*64+b]; hll[0] = s_all[g] - M - logf(L); }
  } else if (w == 1){
    float v = s_all[128+lane];
    float M = wmaxr(v);
    float L = wsum(__expf(v-M));
    if (lane == 0){ int g = gold_c[t*64+b]; hll[1] = s_all[128+g] - M - logf(L); }
  } else if (w == 2){
    float v = (lane < 16) ? s_all[192+lane] : -INFINITY;
    float M = wmaxr(v);
    float L = wsum((lane < 16) ? __expf(v-M) : 0.f);
    if (lane == 0){ int g = gold_t[t*64+b]; hll[2] = s_all[192+g] - M - logf(L); }
  }
  __syncthreads();
  if (threadIdx.x == 0) atomicAdd(loss, -(hll[0]+hll[1]+hll[2]));
}

// ---------------- launcher ----------------

extern "C" void kernel_launch(void* const* d_in, const int* in_sizes, int n_in,
                              void* d_out, int out_size, void* d_ws, size_t ws_size,
                              hipStream_t stream){
  const float* memory    = (const float*)d_in[0];
  const float* enc_col   = (const float*)d_in[1];
  const float* enc_tab   = (const float*)d_in[2];
  const float* init_h    = (const float*)d_in[3];
  const float* init_c    = (const float*)d_in[4];
  const float* prev_emb  = (const float*)d_in[5];
  const float* node_emb  = (const float*)d_in[6];
  const float* W_att     = (const float*)d_in[7];
  // d_in[8] = b_att: cancels exactly in every log-softmax head — unused.
  const float* W_tgt     = (const float*)d_in[9];
  const float* b_tgt     = (const float*)d_in[10];
  const float* W_out     = (const float*)d_in[11];
  const float* b_out     = (const float*)d_in[12];
  const float* W_ih      = (const float*)d_in[13];
  const float* W_hh      = (const float*)d_in[14];
  const float* b_ih      = (const float*)d_in[15];
  const float* b_hh      = (const float*)d_in[16];
  const float* action_emb= (const float*)d_in[17];
  const int*   mem_mask  = (const int*)d_in[18];
  const int*   col_mask  = (const int*)d_in[19];
  const int*   tab_mask  = (const int*)d_in[20];
  const int*   gold_a    = (const int*)d_in[21];
  const int*   gold_c    = (const int*)d_in[22];
  const int*   gold_t    = (const int*)d_in[23];

  float* ws   = (float*)d_ws;
  float* WcTk = ws;                      // 1048576
  float* ub   = WcTk + 1048576;          // 1024
  float* hT   = ub   + 1024;             // 65536
  float* cT   = hT   + 65536;            // 65536
  float* q    = cT   + 65536;            // 65536
  float* u    = q    + 65536;            // 65536
  float* ctxT = u    + 65536;            // 65536
  float* pa   = ctxT + 65536;            // 532480
  float* part = pa   + 532480;           // max(skg*4096, SKQ*2048)*64
  float* loss = (float*)d_out;

  size_t fixedf = 1048576 + 1024 + (size_t)5*65536 + 532480;
  size_t availf = (ws_size/4 > fixedf) ? (ws_size/4 - fixedf) : 0;
  int skg = 16;
  if (availf < (size_t)16*4096*64) skg = 8;
  if (availf < (size_t)8*4096*64)  skg = 4;

  k_init       <<<1,   64, 0, stream>>>(loss);
  k_transpose64<<<32, 256, 0, stream>>>(init_h, hT);
  k_transpose64<<<32, 256, 0, stream>>>(init_c, cT);
  k_wctk2      <<<256,256, 0, stream>>>(W_att, W_out, WcTk);
  k_ubias2     <<<256,256, 0, stream>>>(W_att, b_out, ub);
  k_qu_gemm    <<<32*SKQ,256,0,stream>>>(hT, W_tgt, WcTk, part);
  k_qu_reduce  <<<512,256, 0, stream>>>(part, b_tgt, ub, q, u);

  for (int t = 0; t < 24; ++t){
    k_attn_part <<<512, 256, 0, stream>>>(memory, q, mem_mask, pa);
    k_attn_merge<<<64,  256, 0, stream>>>(pa, ctxT);
    k_gates_gemm<<<32*skg,256,0, stream>>>(prev_emb + (size_t)t*65536,
                                           node_emb + (size_t)t*65536,
                                           ctxT, hT, W_ih, W_hh, part, skg);
    k_lstm      <<<256, 256, 0, stream>>>(part, b_ih, b_hh, hT, cT, skg);
    k_qu_gemm   <<<32*SKQ,256,0,stream>>>(hT, W_tgt, WcTk, part);
    k_qu_reduce <<<512, 256, 0, stream>>>(part, b_tgt, ub, q, u);
    k_scores    <<<64,  256, 0, stream>>>(u, action_emb, enc_col, enc_tab,
                                          col_mask, tab_mask, gold_a, gold_c, gold_t,
                                          t, loss);
  }
}

// Round 5
// 2775.163 us; speedup vs baseline: 3.7673x; 1.1373x over previous
//
#include <hip/hip_runtime.h>
#include <math.h>

#define NEGB (-1e9f)
typedef float4 f4;

__device__ __forceinline__ float wsum(float v){
#pragma unroll
  for (int m = 32; m; m >>= 1) v += __shfl_xor(v, m, 64);
  return v;
}
__device__ __forceinline__ float wmaxr(float v){
#pragma unroll
  for (int m = 32; m; m >>= 1) v = fmaxf(v, __shfl_xor(v, m, 64));
  return v;
}
__device__ __forceinline__ f4 ld4(const float* p){ return *reinterpret_cast<const f4*>(p); }
__device__ __forceinline__ void st4(float* p, f4 v){ *reinterpret_cast<f4*>(p) = v; }
__device__ __forceinline__ float dot4(f4 a, f4 b){
  return a.x*b.x + a.y*b.y + a.z*b.z + a.w*b.w;
}
__device__ __forceinline__ float sigm(float x){ return 1.0f/(1.0f + __expf(-x)); }

#define FMA4(a, s, v) { (a).x += (s)*(v).x; (a).y += (s)*(v).y; (a).z += (s)*(v).z; (a).w += (s)*(v).w; }

// ---------------- prologue kernels ----------------

__global__ __launch_bounds__(64) void k_init(float* __restrict__ loss){
  if (threadIdx.x == 0) *loss = 0.f;
}

// in [64][1024] -> out [1024][64]; grid 32
__global__ __launch_bounds__(256) void k_transpose64(const float* __restrict__ in,
    float* __restrict__ out){
  __shared__ float t64[64][33];
  int tid = threadIdx.x;
  int k0 = blockIdx.x * 32;
  int b = tid >> 2, kk = (tid & 3) * 8;
  f4 v0 = ld4(in + (size_t)b*1024 + k0 + kk);
  f4 v1 = ld4(in + (size_t)b*1024 + k0 + kk + 4);
  t64[b][kk+0]=v0.x; t64[b][kk+1]=v0.y; t64[b][kk+2]=v0.z; t64[b][kk+3]=v0.w;
  t64[b][kk+4]=v1.x; t64[b][kk+5]=v1.y; t64[b][kk+6]=v1.z; t64[b][kk+7]=v1.w;
  __syncthreads();
  int b2 = tid & 63, kg = tid >> 6;
#pragma unroll
  for (int i=0;i<8;++i){
    int kk2 = kg*8 + i;
    out[(size_t)(k0+kk2)*64 + b2] = t64[b2][kk2];
  }
}

// WcTk[d][ep] = sum_e W_out[d][e] * W_att[ep][e]. Tiled NT GEMM, 64x64 tile,
// 4x4/thread, K=1024, grid 256 (16 d-tiles x 16 ep-tiles).
__global__ __launch_bounds__(256) void k_wctk2(const float* __restrict__ W_att,
    const float* __restrict__ W_out, float* __restrict__ WcTk){
  __shared__ float Al[16][68];
  __shared__ float Bl[16][68];
  int tid = threadIdx.x;
  int d0 = (blockIdx.x >> 4) * 64, ep0 = (blockIdx.x & 15) * 64;
  int srow = tid >> 2, skk = (tid & 3) * 4;
  int m0 = (tid >> 4) * 4, n0 = (tid & 15) * 4;
  f4 acc[4];
#pragma unroll
  for (int i=0;i<4;++i){ acc[i].x=0;acc[i].y=0;acc[i].z=0;acc[i].w=0; }
  f4 pa = ld4(W_out + (size_t)(d0+srow)*1024 + skk);
  f4 pb = ld4(W_att + (size_t)(ep0+srow)*1024 + skk);
  for (int kc = 0; kc < 1024; kc += 16){
#pragma unroll
    for (int j=0;j<4;++j){
      (&Al[skk][srow])[j*68] = (&pa.x)[j];
      (&Bl[skk][srow])[j*68] = (&pb.x)[j];
    }
    __syncthreads();
    if (kc + 16 < 1024){
      pa = ld4(W_out + (size_t)(d0+srow)*1024 + kc + 16 + skk);
      pb = ld4(W_att + (size_t)(ep0+srow)*1024 + kc + 16 + skk);
    }
#pragma unroll
    for (int k=0;k<16;++k){
      f4 a4 = ld4(&Al[k][m0]);
      f4 b4 = ld4(&Bl[k][n0]);
      FMA4(acc[0], a4.x, b4);
      FMA4(acc[1], a4.y, b4);
      FMA4(acc[2], a4.z, b4);
      FMA4(acc[3], a4.w, b4);
    }
    __syncthreads();
  }
#pragma unroll
  for (int i=0;i<4;++i)
    st4(WcTk + (size_t)(d0+m0+i)*1024 + ep0 + n0, acc[i]);
}

// ub[ep] = dot(W_att[ep,:], b_out). grid 256 x 256 (one wave per ep).
__global__ __launch_bounds__(256) void k_ubias2(const float* __restrict__ W_att,
    const float* __restrict__ b_out, float* __restrict__ ub){
  int w = threadIdx.x >> 6, lane = threadIdx.x & 63;
  int ep = blockIdx.x*4 + w;
  const float* arow = W_att + (size_t)ep*1024;
  float acc = 0.f;
#pragma unroll
  for (int i=0;i<4;++i)
    acc += dot4(ld4(arow + i*256 + lane*4), ld4(b_out + i*256 + lane*4));
  float s = wsum(acc);
  if (lane == 0) ub[ep] = s;
}

// ---------------- per-step kernels ----------------

// q/u GEMM partials: rows n<1024 from W_tgt[d][n] (k-major), else WcTk[d][ep].
// X = hT [1024][64]. 64x64 tile, 4x4/thread, grid 32*SKQ. SKQ=8.
#define SKQ 8
__global__ __launch_bounds__(256) void k_qu_gemm(
    const float* __restrict__ hT, const float* __restrict__ W_tgt,
    const float* __restrict__ WcTk, float* __restrict__ part){
  __shared__ float Al[16][68];
  __shared__ float Xl[16][68];
  int tid = threadIdx.x;
  int rt = blockIdx.x >> 3, ks = blockIdx.x & 7;
  int n0g = rt*64;
  int kbeg = ks*128;
  int skk = tid >> 4, sn4 = (tid & 15) * 4;
  int m0 = (tid >> 4) * 4, n0 = (tid & 15) * 4;
  const float* Wsrc = (rt < 16) ? (W_tgt + n0g) : (WcTk + (n0g - 1024));
  f4 acc[4];
#pragma unroll
  for (int i=0;i<4;++i){ acc[i].x=0;acc[i].y=0;acc[i].z=0;acc[i].w=0; }
  f4 pa = ld4(Wsrc + (size_t)(kbeg+skk)*1024 + sn4);
  f4 px = ld4(hT + (size_t)(kbeg+skk)*64 + sn4);
  for (int kc = kbeg; kc < kbeg+128; kc += 16){
    st4(&Al[skk][sn4], pa);
    st4(&Xl[skk][sn4], px);
    __syncthreads();
    if (kc + 16 < kbeg+128){
      pa = ld4(Wsrc + (size_t)(kc+16+skk)*1024 + sn4);
      px = ld4(hT + (size_t)(kc+16+skk)*64 + sn4);
    }
#pragma unroll
    for (int k=0;k<16;++k){
      f4 a4 = ld4(&Al[k][m0]);
      f4 x4 = ld4(&Xl[k][n0]);
      FMA4(acc[0], a4.x, x4);
      FMA4(acc[1], a4.y, x4);
      FMA4(acc[2], a4.z, x4);
      FMA4(acc[3], a4.w, x4);
    }
    __syncthreads();
  }
#pragma unroll
  for (int i=0;i<4;++i)
    st4(part + ((size_t)ks*2048 + n0g + m0 + i)*64 + n0, acc[i]);
}

// reduce + bias for q/u. grid 512 x 256
__global__ __launch_bounds__(256) void k_qu_reduce(const float* __restrict__ part,
    const float* __restrict__ b_tgt, const float* __restrict__ ub,
    float* __restrict__ q, float* __restrict__ u){
  int idx = blockIdx.x*256 + threadIdx.x;
  int b = idx & 63, n = idx >> 6;
  float s = 0.f;
#pragma unroll
  for (int ks=0; ks<SKQ; ++ks) s += part[((size_t)ks*2048 + n)*64 + b];
  if (n < 1024) q[(size_t)b*1024 + n] = s + b_tgt[n];
  else          u[(size_t)b*1024 + n - 1024] = s + ub[n - 1024];
}

// Gate GEMM partials: G[4096][64] = [W_ih|W_hh] x [prev;node;ctxT;hT].
// M-tile 128, 4x8/thread, grid 32*sk x 256.
__device__ __forceinline__ f4 gx_load(const float* prev_e, const float* node_e,
    const float* ctxT, const float* hT, int kc, int tid){
  int sel = kc >> 10;
  if (sel <= 1){
    const float* src = (sel==0) ? prev_e : node_e;       // [64][1024] row-major
    int b = tid >> 2, kk = (tid & 3)*4;
    return ld4(src + (size_t)b*1024 + (kc & 1023) + kk);
  } else {
    const float* src = (sel==2) ? (ctxT + (size_t)(kc-2048)*64)
                                : (hT  + (size_t)(kc-3072)*64);  // [1024][64] k-major
    int kk = tid >> 4, b4 = (tid & 15)*4;
    return ld4(src + (size_t)kk*64 + b4);
  }
}
__device__ __forceinline__ void gx_store(float Xl[16][68], f4 v, int kc, int tid){
  if ((kc >> 10) <= 1){
    int b = tid >> 2, kk = (tid & 3)*4;
    Xl[kk+0][b]=v.x; Xl[kk+1][b]=v.y; Xl[kk+2][b]=v.z; Xl[kk+3][b]=v.w;
  } else {
    int kk = tid >> 4, b4 = (tid & 15)*4;
    st4(&Xl[kk][b4], v);
  }
}
__device__ __forceinline__ void gw_load(const float* W_ih, const float* W_hh,
    int r, int kc, int c8, f4* w){
  const float* src = (kc < 3072) ? (W_ih + (size_t)r*3072 + kc + c8)
                                 : (W_hh + (size_t)r*1024 + (kc-3072) + c8);
  w[0] = ld4(src); w[1] = ld4(src + 4);
}

__global__ __launch_bounds__(256) void k_gates_gemm(
    const float* __restrict__ prev_e, const float* __restrict__ node_e,
    const float* __restrict__ ctxT, const float* __restrict__ hT,
    const float* __restrict__ W_ih, const float* __restrict__ W_hh,
    float* __restrict__ part, int sk){
  __shared__ float Wl[16][132];
  __shared__ float Xl[16][68];
  int tid = threadIdx.x;
  int rt = blockIdx.x / sk, ks = blockIdx.x - rt*sk;
  int r0 = rt*128;
  int kper = 4096/sk;
  int kbeg = ks*kper, kend = kbeg + kper;
  int srow = tid >> 1, c8 = (tid & 1)*8;   // stage: row r0+srow, cols c8..c8+7
  int m0 = (tid >> 3)*4, n0 = (tid & 7)*8;
  f4 acc[4][2];
#pragma unroll
  for (int i=0;i<4;++i){
    acc[i][0].x=0;acc[i][0].y=0;acc[i][0].z=0;acc[i][0].w=0;
    acc[i][1].x=0;acc[i][1].y=0;acc[i][1].z=0;acc[i][1].w=0;
  }
  f4 pw[2];
  gw_load(W_ih, W_hh, r0+srow, kbeg, c8, pw);
  f4 px = gx_load(prev_e, node_e, ctxT, hT, kbeg, tid);
  for (int kc = kbeg; kc < kend; kc += 16){
#pragma unroll
    for (int j=0;j<4;++j){
      Wl[c8+j][srow]   = (&pw[0].x)[j];
      Wl[c8+4+j][srow] = (&pw[1].x)[j];
    }
    gx_store(Xl, px, kc, tid);
    __syncthreads();
    if (kc + 16 < kend){
      gw_load(W_ih, W_hh, r0+srow, kc+16, c8, pw);
      px = gx_load(prev_e, node_e, ctxT, hT, kc+16, tid);
    }
#pragma unroll
    for (int k=0;k<16;++k){
      f4 w4 = ld4(&Wl[k][m0]);
      f4 x0 = ld4(&Xl[k][n0]);
      f4 x1 = ld4(&Xl[k][n0+4]);
      FMA4(acc[0][0], w4.x, x0); FMA4(acc[0][1], w4.x, x1);
      FMA4(acc[1][0], w4.y, x0); FMA4(acc[1][1], w4.y, x1);
      FMA4(acc[2][0], w4.z, x0); FMA4(acc[2][1], w4.z, x1);
      FMA4(acc[3][0], w4.w, x0); FMA4(acc[3][1], w4.w, x1);
    }
    __syncthreads();
  }
#pragma unroll
  for (int i=0;i<4;++i){
    float* dst = part + ((size_t)ks*4096 + r0 + m0 + i)*64 + n0;
    st4(dst, acc[i][0]); st4(dst+4, acc[i][1]);
  }
}

// reduce + LSTM pointwise. grid 256 x 256
__global__ __launch_bounds__(256) void k_lstm(const float* __restrict__ part,
    const float* __restrict__ b_ih, const float* __restrict__ b_hh,
    float* __restrict__ hT, float* __restrict__ cT, int sk){
  int idx = blockIdx.x*256 + threadIdx.x;   // b fastest
  int b = idx & 63, j = idx >> 6;
  float g[4];
#pragma unroll
  for (int gg=0; gg<4; ++gg){
    int r = gg*1024 + j;
    float s = b_ih[r] + b_hh[r];
    for (int ks=0; ks<sk; ++ks) s += part[((size_t)ks*4096 + r)*64 + b];
    g[gg] = s;
  }
  float c_old = cT[idx];
  float cn = sigm(g[1])*c_old + sigm(g[0])*tanhf(g[2]);
  float hn = sigm(g[3])*tanhf(cn);
  hT[idx] = hn;
  cT[idx] = cn;
}

// attention partials. grid 512 (b x 8 chunks) x 256
__global__ __launch_bounds__(256) void k_attn_part(const float* __restrict__ memory,
    const float* __restrict__ q, const int* __restrict__ mmask,
    float* __restrict__ pa){
  __shared__ float cs[4][1024];
  __shared__ float mw[4], lw[4];
  int b = blockIdx.x >> 3, sc = blockIdx.x & 7;
  int w = threadIdx.x >> 6, lane = threadIdx.x & 63;
  const float* qb = q + (size_t)b*1024;
  f4 qf[4];
#pragma unroll
  for (int i=0;i<4;++i) qf[i] = ld4(qb + i*256 + lane*4);
  float m = -INFINITY, l = 0.f;
  f4 ca[4];
#pragma unroll
  for (int i=0;i<4;++i){ ca[i].x=0;ca[i].y=0;ca[i].z=0;ca[i].w=0; }
  for (int rr=0; rr<8; ++rr){
    int s = sc*32 + w*8 + rr;
    const float* mr = memory + ((size_t)b*256 + s)*1024;
    f4 a[4];
#pragma unroll
    for (int i=0;i<4;++i) a[i] = ld4(mr + i*256 + lane*4);
    float acc = 0.f;
#pragma unroll
    for (int i=0;i<4;++i) acc += dot4(a[i], qf[i]);
    float sv = wsum(acc) + (mmask[b*256+s]==1 ? NEGB : 0.f);
    float mn = fmaxf(m, sv);
    float al = __expf(m - mn);
    float p  = __expf(sv - mn);
    l = l*al + p;
#pragma unroll
    for (int i=0;i<4;++i){
      ca[i].x = ca[i].x*al + a[i].x*p;
      ca[i].y = ca[i].y*al + a[i].y*p;
      ca[i].z = ca[i].z*al + a[i].z*p;
      ca[i].w = ca[i].w*al + a[i].w*p;
    }
    m = mn;
  }
#pragma unroll
  for (int i=0;i<4;++i) st4(&cs[w][i*256 + lane*4], ca[i]);
  if (lane == 0){ mw[w] = m; lw[w] = l; }
  __syncthreads();
  int k4 = threadIdx.x*4;
  float M = fmaxf(fmaxf(mw[0],mw[1]), fmaxf(mw[2],mw[3]));
  float c0 = __expf(mw[0]-M), c1 = __expf(mw[1]-M);
  float c2 = __expf(mw[2]-M), c3 = __expf(mw[3]-M);
  float L = c0*lw[0] + c1*lw[1] + c2*lw[2] + c3*lw[3];
  f4 t0 = ld4(&cs[0][k4]), t1 = ld4(&cs[1][k4]);
  f4 t2 = ld4(&cs[2][k4]), t3 = ld4(&cs[3][k4]);
  f4 o;
  o.x = c0*t0.x + c1*t1.x + c2*t2.x + c3*t3.x;
  o.y = c0*t0.y + c1*t1.y + c2*t2.y + c3*t3.y;
  o.z = c0*t0.z + c1*t1.z + c2*t2.z + c3*t3.z;
  o.w = c0*t0.w + c1*t1.w + c2*t2.w + c3*t3.w;
  float* pb = pa + (size_t)(b*8+sc)*1040;
  st4(pb + k4, o);
  if (threadIdx.x == 0){ pb[1024] = M; pb[1025] = L; }
}

// merge 8 partials -> ctxT [1024][64]. grid 64 x 256
__global__ __launch_bounds__(256) void k_attn_merge(const float* __restrict__ pa,
    float* __restrict__ ctxT){
  int b = blockIdx.x;
  int tid = threadIdx.x;
  const float* pb = pa + (size_t)b*8*1040;
  float mm[8], ll[8];
#pragma unroll
  for (int s=0;s<8;++s){ mm[s] = pb[s*1040 + 1024]; ll[s] = pb[s*1040 + 1025]; }
  float M = mm[0];
#pragma unroll
  for (int s=1;s<8;++s) M = fmaxf(M, mm[s]);
  float co[8], L = 0.f;
#pragma unroll
  for (int s=0;s<8;++s){ co[s] = __expf(mm[s]-M); L += co[s]*ll[s]; }
  float inv = 1.f / L;
  int k4 = tid*4;
#pragma unroll
  for (int i=0;i<4;++i){
    int k = k4 + i;
    float v = 0.f;
#pragma unroll
    for (int s=0;s<8;++s) v += co[s]*pb[s*1040 + k];
    ctxT[(size_t)k*64 + b] = v * inv;
  }
}

// scoring heads: row-per-thread, LDS-staged E tiles + u broadcast, then
// per-head log-softmax + gold gather + loss. grid 64 x 256.
__global__ __launch_bounds__(256) void k_scores2(
    const float* __restrict__ u, const float* __restrict__ action_emb,
    const float* __restrict__ enc_col, const float* __restrict__ enc_tab,
    const int* __restrict__ col_mask, const int* __restrict__ tab_mask,
    const int* __restrict__ gold_a, const int* __restrict__ gold_c,
    const int* __restrict__ gold_t, int t, float* __restrict__ loss){
  __shared__ float Es[208][65];   // row-major, 65 pad: bank=(row+k)%32 -> <=2-way
  __shared__ float us[1024];
  __shared__ float s_all[208];
  __shared__ float hll[3];
  int b = blockIdx.x, tid = threadIdx.x;
  st4(&us[tid*4], ld4(u + (size_t)b*1024 + tid*4));
  float acc = 0.f;
  f4 pv[13];
  // stage rows: idx = i*256+tid in [0,3328): row=idx>>4, kk=(idx&15)*4
#define SC_LOAD(c) {                                                         \
    _Pragma("unroll")                                                        \
    for (int i=0;i<13;++i){                                                  \
      int idx = i*256 + tid;                                                 \
      int row = idx >> 4, kk2 = (idx & 15)*4;                                \
      int k = (c)*64 + kk2;                                                  \
      const float* src;                                                      \
      if (row < 128)      src = action_emb + (size_t)row*1024 + k;           \
      else if (row < 192) src = enc_col + ((size_t)b*64 + (row-128))*1024 + k;\
      else                src = enc_tab + ((size_t)b*16 + (row-192))*1024 + k;\
      pv[i] = ld4(src);                                                      \
    } }
  SC_LOAD(0);
  for (int c = 0; c < 16; ++c){
#pragma unroll
    for (int i=0;i<13;++i){
      int idx = i*256 + tid;
      int row = idx >> 4, kk2 = (idx & 15)*4;
      Es[row][kk2+0] = pv[i].x; Es[row][kk2+1] = pv[i].y;
      Es[row][kk2+2] = pv[i].z; Es[row][kk2+3] = pv[i].w;
    }
    __syncthreads();
    if (c + 1 < 16) SC_LOAD(c + 1);
    if (tid < 208){
#pragma unroll
      for (int j=0;j<64;++j)
        acc += Es[tid][j] * us[c*64 + j];
    }
    __syncthreads();
  }
#undef SC_LOAD
  if (tid < 208){
    float bias = 0.f;
    if (tid >= 192)      bias = (tab_mask[b*16 + (tid-192)]==1) ? NEGB : 0.f;
    else if (tid >= 128) bias = (col_mask[b*64 + (tid-128)]==1) ? NEGB : 0.f;
    s_all[tid] = acc + bias;
  }
  __syncthreads();
  int w = tid >> 6, lane = tid & 63;
  if (w == 0){
    float v0 = s_all[lane], v1 = s_all[64+lane];
    float M = wmaxr(fmaxf(v0, v1));
    float L = wsum(__expf(v0-M) + __expf(v1-M));
    if (lane == 0){ int g = gold_a[t*64+b]; hll[0] = s_all[g] - M - logf(L); }
  } else if (w == 1){
    float v = s_all[128+lane];
    float M = wmaxr(v);
    float L = wsum(__expf(v-M));
    if (lane == 0){ int g = gold_c[t*64+b]; hll[1] = s_all[128+g] - M - logf(L); }
  } else if (w == 2){
    float v = (lane < 16) ? s_all[192+lane] : -INFINITY;
    float M = wmaxr(v);
    float L = wsum((lane < 16) ? __expf(v-M) : 0.f);
    if (lane == 0){ int g = gold_t[t*64+b]; hll[2] = s_all[192+g] - M - logf(L); }
  }
  __syncthreads();
  if (tid == 0) atomicAdd(loss, -(hll[0]+hll[1]+hll[2]));
}

// ---------------- launcher ----------------

extern "C" void kernel_launch(void* const* d_in, const int* in_sizes, int n_in,
                              void* d_out, int out_size, void* d_ws, size_t ws_size,
                              hipStream_t stream){
  const float* memory    = (const float*)d_in[0];
  const float* enc_col   = (const float*)d_in[1];
  const float* enc_tab   = (const float*)d_in[2];
  const float* init_h    = (const float*)d_in[3];
  const float* init_c    = (const float*)d_in[4];
  const float* prev_emb  = (const float*)d_in[5];
  const float* node_emb  = (const float*)d_in[6];
  const float* W_att     = (const float*)d_in[7];
  // d_in[8] = b_att: cancels exactly in every log-softmax head — unused.
  const float* W_tgt     = (const float*)d_in[9];
  const float* b_tgt     = (const float*)d_in[10];
  const float* W_out     = (const float*)d_in[11];
  const float* b_out     = (const float*)d_in[12];
  const float* W_ih      = (const float*)d_in[13];
  const float* W_hh      = (const float*)d_in[14];
  const float* b_ih      = (const float*)d_in[15];
  const float* b_hh      = (const float*)d_in[16];
  const float* action_emb= (const float*)d_in[17];
  const int*   mem_mask  = (const int*)d_in[18];
  const int*   col_mask  = (const int*)d_in[19];
  const int*   tab_mask  = (const int*)d_in[20];
  const int*   gold_a    = (const int*)d_in[21];
  const int*   gold_c    = (const int*)d_in[22];
  const int*   gold_t    = (const int*)d_in[23];

  float* ws   = (float*)d_ws;
  float* WcTk = ws;                      // 1048576
  float* ub   = WcTk + 1048576;          // 1024
  float* hT   = ub   + 1024;             // 65536
  float* cT   = hT   + 65536;            // 65536
  float* q    = cT   + 65536;            // 65536
  float* u    = q    + 65536;            // 65536
  float* ctxT = u    + 65536;            // 65536
  float* pa   = ctxT + 65536;            // 532480
  float* part = pa   + 532480;           // max(skg*4096, SKQ*2048)*64
  float* loss = (float*)d_out;

  size_t fixedf = 1048576 + 1024 + (size_t)5*65536 + 532480;
  size_t availf = (ws_size/4 > fixedf) ? (ws_size/4 - fixedf) : 0;
  int skg = 16;
  if (availf < (size_t)16*4096*64) skg = 8;
  if (availf < (size_t)8*4096*64)  skg = 4;

  k_init       <<<1,   64, 0, stream>>>(loss);
  k_transpose64<<<32, 256, 0, stream>>>(init_h, hT);
  k_transpose64<<<32, 256, 0, stream>>>(init_c, cT);
  k_wctk2      <<<256,256, 0, stream>>>(W_att, W_out, WcTk);
  k_ubias2     <<<256,256, 0, stream>>>(W_att, b_out, ub);
  k_qu_gemm    <<<32*SKQ,256,0,stream>>>(hT, W_tgt, WcTk, part);
  k_qu_reduce  <<<512,256, 0, stream>>>(part, b_tgt, ub, q, u);

  for (int t = 0; t < 24; ++t){
    k_attn_part <<<512, 256, 0, stream>>>(memory, q, mem_mask, pa);
    k_attn_merge<<<64,  256, 0, stream>>>(pa, ctxT);
    k_gates_gemm<<<32*skg,256,0, stream>>>(prev_emb + (size_t)t*65536,
                                           node_emb + (size_t)t*65536,
                                           ctxT, hT, W_ih, W_hh, part, skg);
    k_lstm      <<<256, 256, 0, stream>>>(part, b_ih, b_hh, hT, cT, skg);
    k_qu_gemm   <<<32*SKQ,256,0,stream>>>(hT, W_tgt, WcTk, part);
    k_qu_reduce <<<512, 256, 0, stream>>>(part, b_tgt, ub, q, u);
    k_scores2   <<<64,  256, 0, stream>>>(u, action_emb, enc_col, enc_tab,
                                          col_mask, tab_mask, gold_a, gold_c, gold_t,
                                          t, loss);
  }
}